// Round 1
// baseline (351.100 us; speedup 1.0000x reference)
//
#include <hip/hip_runtime.h>
#include <hip/hip_bf16.h>

typedef __attribute__((ext_vector_type(8))) short short8;
typedef __attribute__((ext_vector_type(4))) float f32x4;

constexpr int BATCH  = 4;
constexpr int NSRC   = 2048;
constexpr int NTGT   = 8192;
constexpr int C_IN   = 256;
constexpr int C_SKIP = 128;
constexpr int DIN    = 384;   // C_IN + C_SKIP
constexpr int HID    = 256;
constexpr int MROWS  = BATCH * NTGT;  // 32768

// ---------------- KNN: top-3 nearest sources per target ----------------
__global__ __launch_bounds__(256) void knn_kernel(const float* __restrict__ pos,
                                                  const float* __restrict__ pos_skip,
                                                  int* __restrict__ idxo,
                                                  float* __restrict__ wo) {
    __shared__ float4 sp[NSRC];
    const int t0 = blockIdx.x * 256;          // 256 targets per block, never crosses batch
    const int b  = t0 / NTGT;
    const float* ps = pos + (size_t)b * NSRC * 3;
    for (int j = threadIdx.x; j < NSRC; j += 256) {
        float x = ps[j * 3 + 0], y = ps[j * 3 + 1], z = ps[j * 3 + 2];
        float s2 = __fadd_rn(__fadd_rn(__fmul_rn(x, x), __fmul_rn(y, y)), __fmul_rn(z, z));
        sp[j] = make_float4(x, y, z, s2);
    }
    __syncthreads();
    const int tr = t0 + threadIdx.x;
    const float px = pos_skip[tr * 3 + 0], py = pos_skip[tr * 3 + 1], pz = pos_skip[tr * 3 + 2];
    const float pt2 = __fadd_rn(__fadd_rn(__fmul_rn(px, px), __fmul_rn(py, py)), __fmul_rn(pz, pz));
    float bd0 = 3e38f, bd1 = 3e38f, bd2 = 3e38f;
    int   bi0 = 0, bi1 = 0, bi2 = 0;
    for (int j = 0; j < NSRC; ++j) {
        float4 s = sp[j];
        // replicate reference's expanded formula ordering: (pt2 + ps2) - 2*dot
        float dot = __fadd_rn(__fadd_rn(__fmul_rn(px, s.x), __fmul_rn(py, s.y)), __fmul_rn(pz, s.z));
        float d2  = __fsub_rn(__fadd_rn(pt2, s.w), __fmul_rn(2.0f, dot));
        if (d2 < bd0)      { bd2 = bd1; bi2 = bi1; bd1 = bd0; bi1 = bi0; bd0 = d2; bi0 = j; }
        else if (d2 < bd1) { bd2 = bd1; bi2 = bi1; bd1 = d2;  bi1 = j; }
        else if (d2 < bd2) { bd2 = d2;  bi2 = j; }
    }
    idxo[tr * 3 + 0] = bi0; idxo[tr * 3 + 1] = bi1; idxo[tr * 3 + 2] = bi2;
    wo[tr * 3 + 0] = 1.0f / fmaxf(bd0, 1e-16f);
    wo[tr * 3 + 1] = 1.0f / fmaxf(bd1, 1e-16f);
    wo[tr * 3 + 2] = 1.0f / fmaxf(bd2, 1e-16f);
}

// ---------------- interpolate + concat -> H0 (bf16, [MROWS][DIN]) ----------------
__global__ __launch_bounds__(256) void build_h_kernel(const float* __restrict__ x,
                                                      const float* __restrict__ xs,
                                                      const int* __restrict__ idxo,
                                                      const float* __restrict__ wo,
                                                      __hip_bfloat16* __restrict__ H0) {
    const int r    = blockIdx.x * 4 + (threadIdx.x >> 6);
    const int lane = threadIdx.x & 63;
    const int b    = r / NTGT;
    const float* xb = x + (size_t)b * NSRC * C_IN;
    const float w0 = wo[r * 3 + 0], w1 = wo[r * 3 + 1], w2 = wo[r * 3 + 2];
    const float inv = 1.0f / ((w0 + w1) + w2);
    const float* f0 = xb + (size_t)idxo[r * 3 + 0] * C_IN;
    const float* f1 = xb + (size_t)idxo[r * 3 + 1] * C_IN;
    const float* f2 = xb + (size_t)idxo[r * 3 + 2] * C_IN;
    __hip_bfloat16* o = H0 + (size_t)r * DIN;
#pragma unroll
    for (int k = 0; k < 4; ++k) {
        int c = lane + k * 64;
        float v = ((w0 * f0[c] + w1 * f1[c]) + w2 * f2[c]) * inv;
        o[c] = __float2bfloat16(v);
    }
    const float* srow = xs + (size_t)r * C_SKIP;
#pragma unroll
    for (int k = 0; k < 2; ++k) {
        int c = lane + k * 64;
        o[C_IN + c] = __float2bfloat16(srow[c]);
    }
}

// ---------------- W1 -> bf16 transposed [HID][DIN] ----------------
__global__ __launch_bounds__(256) void wconv1_kernel(const float* __restrict__ W1,
                                                     __hip_bfloat16* __restrict__ W1T) {
    int n = blockIdx.x;
    for (int k = threadIdx.x; k < DIN; k += 256)
        W1T[(size_t)n * DIN + k] = __float2bfloat16(W1[(size_t)k * HID + n]);
}

// ---------------- GEMM: out = relu(A @ W + bias), plus column sum/sumsq ----------------
// A: [MROWS][K] bf16 row-major; WT: [HID][K] bf16 (i.e. W transposed)
template <int K, bool OUT_BF16>
__global__ __launch_bounds__(256) void gemm_kernel(const __hip_bfloat16* __restrict__ A,
                                                   const __hip_bfloat16* __restrict__ WT,
                                                   const float* __restrict__ bias,
                                                   void* __restrict__ outp,
                                                   float* __restrict__ colsum,
                                                   float* __restrict__ colsq) {
    __shared__ short As[128 * 40];  // 128 rows x 32 cols, padded stride 40
    const int t = threadIdx.x;
    const int m0 = blockIdx.x * 128, n0 = blockIdx.y * 128;
    const int wid = t >> 6, lane = t & 63;
    const int wr = wid >> 1, wc = wid & 1;
    const int l15 = lane & 15, l4 = lane >> 4;
    f32x4 acc[4][4] = {};
    const short* Ash = (const short*)A;
    const short* Wsh = (const short*)WT;
    for (int kt = 0; kt < K / 32; ++kt) {
        __syncthreads();
#pragma unroll
        for (int c = t; c < 512; c += 256) {
            int row = c >> 2, col8 = (c & 3) * 8;
            short8 v = *(const short8*)(Ash + (size_t)(m0 + row) * K + kt * 32 + col8);
            *(short8*)(&As[row * 40 + col8]) = v;
        }
        __syncthreads();
        short8 af[4], bfr[4];
#pragma unroll
        for (int mi = 0; mi < 4; ++mi)
            af[mi] = *(const short8*)(&As[(wr * 64 + mi * 16 + l15) * 40 + l4 * 8]);
#pragma unroll
        for (int ni = 0; ni < 4; ++ni)
            bfr[ni] = *(const short8*)(Wsh + (size_t)(n0 + wc * 64 + ni * 16 + l15) * K + kt * 32 + l4 * 8);
#pragma unroll
        for (int mi = 0; mi < 4; ++mi)
#pragma unroll
            for (int ni = 0; ni < 4; ++ni)
                acc[mi][ni] = __builtin_amdgcn_mfma_f32_16x16x32_bf16(af[mi], bfr[ni], acc[mi][ni], 0, 0, 0);
    }
    // epilogue: bias + relu + store + column stats
    float bv[4];
    int col[4];
#pragma unroll
    for (int ni = 0; ni < 4; ++ni) {
        col[ni] = n0 + wc * 64 + ni * 16 + l15;
        bv[ni] = bias[col[ni]];
    }
    float csum[4] = {0, 0, 0, 0}, csq[4] = {0, 0, 0, 0};
    __hip_bfloat16* ob = (__hip_bfloat16*)outp;
    float* of = (float*)outp;
#pragma unroll
    for (int mi = 0; mi < 4; ++mi) {
#pragma unroll
        for (int r = 0; r < 4; ++r) {
            int rowg = m0 + wr * 64 + mi * 16 + l4 * 4 + r;  // D layout: row=(lane>>4)*4+reg
#pragma unroll
            for (int ni = 0; ni < 4; ++ni) {
                float v = fmaxf(acc[mi][ni][r] + bv[ni], 0.0f);
                if (OUT_BF16) ob[(size_t)rowg * HID + col[ni]] = __float2bfloat16(v);
                else          of[(size_t)rowg * HID + col[ni]] = v;
                csum[ni] += v;
                csq[ni] += v * v;
            }
        }
    }
#pragma unroll
    for (int ni = 0; ni < 4; ++ni) {
        float s = csum[ni], q = csq[ni];
        s += __shfl_xor(s, 16); s += __shfl_xor(s, 32);
        q += __shfl_xor(q, 16); q += __shfl_xor(q, 32);
        if (l4 == 0) {
            atomicAdd(&colsum[col[ni]], s);
            atomicAdd(&colsq[col[ni]], q);
        }
    }
}

// ---------------- BN stats -> scale/shift ----------------
__global__ void finalize_kernel(const float* __restrict__ sum, const float* __restrict__ sq,
                                const float* __restrict__ g, const float* __restrict__ be,
                                float* __restrict__ scale, float* __restrict__ shift) {
    int c = threadIdx.x;
    float mu  = sum[c] * (1.0f / MROWS);
    float var = sq[c] * (1.0f / MROWS) - mu * mu;
    float inv = 1.0f / sqrtf(var + 1e-5f);
    float sc = g[c] * inv;
    scale[c] = sc;
    shift[c] = be[c] - mu * sc;
}

// ---------------- fold BN1 into W2: W2T'[n][k] = scale1[k]*W2[k][n]; bias2' = b2 + shift1@W2 ----------------
__global__ __launch_bounds__(256) void foldw2_kernel(const float* __restrict__ W2,
                                                     const float* __restrict__ b2,
                                                     const float* __restrict__ scale1,
                                                     const float* __restrict__ shift1,
                                                     __hip_bfloat16* __restrict__ W2T,
                                                     float* __restrict__ bias2f) {
    __shared__ float red[256];
    int n = blockIdx.x, k = threadIdx.x;
    float v = W2[(size_t)k * HID + n];
    W2T[(size_t)n * HID + k] = __float2bfloat16(scale1[k] * v);
    red[k] = shift1[k] * v;
    __syncthreads();
    for (int s = 128; s > 0; s >>= 1) {
        if (k < s) red[k] += red[k + s];
        __syncthreads();
    }
    if (k == 0) bias2f[n] = b2[n] + red[0];
}

// ---------------- final BN2 applied in place on d_out (fp32) ----------------
__global__ __launch_bounds__(256) void bn2_kernel(float* __restrict__ out,
                                                  const float* __restrict__ scale2,
                                                  const float* __restrict__ shift2) {
    int idx = blockIdx.x * blockDim.x + threadIdx.x;  // float4 index
    const int total = MROWS * HID / 4;
    for (; idx < total; idx += gridDim.x * blockDim.x) {
        float4 v = ((float4*)out)[idx];
        int c = (idx * 4) & (HID - 1);
        float4 sc = *(const float4*)(scale2 + c);
        float4 sh = *(const float4*)(shift2 + c);
        v.x = sc.x * v.x + sh.x;
        v.y = sc.y * v.y + sh.y;
        v.z = sc.z * v.z + sh.z;
        v.w = sc.w * v.w + sh.w;
        ((float4*)out)[idx] = v;
    }
}

extern "C" void kernel_launch(void* const* d_in, const int* in_sizes, int n_in,
                              void* d_out, int out_size, void* d_ws, size_t ws_size,
                              hipStream_t stream) {
    const float* x    = (const float*)d_in[0];
    const float* pos  = (const float*)d_in[1];
    const float* xs   = (const float*)d_in[3];
    const float* poss = (const float*)d_in[4];
    const float* W1   = (const float*)d_in[6];
    const float* b1   = (const float*)d_in[7];
    const float* g1   = (const float*)d_in[8];
    const float* be1  = (const float*)d_in[9];
    const float* W2   = (const float*)d_in[10];
    const float* b2   = (const float*)d_in[11];
    const float* g2   = (const float*)d_in[12];
    const float* be2  = (const float*)d_in[13];

    char* ws = (char*)d_ws;
    size_t off = 0;
    auto alloc = [&](size_t bytes) -> void* {
        void* p = ws + off;
        off += (bytes + 255) & ~(size_t)255;
        return p;
    };
    int*            idxo  = (int*)alloc((size_t)MROWS * 3 * sizeof(int));
    float*          wo    = (float*)alloc((size_t)MROWS * 3 * sizeof(float));
    __hip_bfloat16* W1T   = (__hip_bfloat16*)alloc((size_t)HID * DIN * 2);
    __hip_bfloat16* W2T   = (__hip_bfloat16*)alloc((size_t)HID * HID * 2);
    float*          stats = (float*)alloc(4 * HID * sizeof(float));
    float *sum1 = stats, *sq1 = stats + HID, *sum2 = stats + 2 * HID, *sq2 = stats + 3 * HID;
    float* sc = (float*)alloc(5 * HID * sizeof(float));
    float *scale1 = sc, *shift1 = sc + HID, *scale2 = sc + 2 * HID, *shift2 = sc + 3 * HID,
          *bias2f = sc + 4 * HID;
    __hip_bfloat16* H0 = (__hip_bfloat16*)alloc((size_t)MROWS * DIN * 2);
    __hip_bfloat16* H1 = (__hip_bfloat16*)alloc((size_t)MROWS * HID * 2);

    hipMemsetAsync(stats, 0, 4 * HID * sizeof(float), stream);

    knn_kernel<<<MROWS / 256, 256, 0, stream>>>(pos, poss, idxo, wo);
    build_h_kernel<<<MROWS / 4, 256, 0, stream>>>(x, xs, idxo, wo, H0);
    wconv1_kernel<<<HID, 256, 0, stream>>>(W1, W1T);
    gemm_kernel<DIN, true><<<dim3(MROWS / 128, 2), 256, 0, stream>>>(H0, W1T, b1, H1, sum1, sq1);
    finalize_kernel<<<1, 256, 0, stream>>>(sum1, sq1, g1, be1, scale1, shift1);
    foldw2_kernel<<<HID, 256, 0, stream>>>(W2, b2, scale1, shift1, W2T, bias2f);
    gemm_kernel<HID, false><<<dim3(MROWS / 128, 2), 256, 0, stream>>>(H1, W2T, bias2f, d_out, sum2, sq2);
    finalize_kernel<<<1, 256, 0, stream>>>(sum2, sq2, g2, be2, scale2, shift2);
    bn2_kernel<<<2048, 256, 0, stream>>>((float*)d_out, scale2, shift2);
}

// Round 2
// 162.643 us; speedup vs baseline: 2.1587x; 2.1587x over previous
//
#include <hip/hip_runtime.h>
#include <hip/hip_bf16.h>

typedef __attribute__((ext_vector_type(8))) short short8;
typedef __attribute__((ext_vector_type(4))) float f32x4;

constexpr int BATCH  = 4;
constexpr int NSRC   = 2048;
constexpr int NTGT   = 8192;
constexpr int C_IN   = 256;
constexpr int C_SKIP = 128;
constexpr int DIN    = 384;   // C_IN + C_SKIP
constexpr int HID    = 256;
constexpr int MROWS  = BATCH * NTGT;  // 32768

// ---------------- KNN: top-3 nearest sources per target ----------------
// 8 lanes per target; each lane scans j = k*8 + s (conflict-free LDS banks,
// broadcast across the 8 target-groups of a wave); butterfly-merge top-3.
__global__ __launch_bounds__(256) void knn_kernel(const float* __restrict__ pos,
                                                  const float* __restrict__ pos_skip,
                                                  int* __restrict__ idxo,
                                                  float* __restrict__ wo) {
    __shared__ float4 sp[NSRC];
    const int t0 = blockIdx.x * 32;           // 32 targets per block, never crosses batch
    const int b  = t0 / NTGT;
    const float* ps = pos + (size_t)b * NSRC * 3;
    for (int j = threadIdx.x; j < NSRC; j += 256) {
        float x = ps[j * 3 + 0], y = ps[j * 3 + 1], z = ps[j * 3 + 2];
        float s2 = __fadd_rn(__fadd_rn(__fmul_rn(x, x), __fmul_rn(y, y)), __fmul_rn(z, z));
        sp[j] = make_float4(x, y, z, s2);
    }
    __syncthreads();
    const int g  = threadIdx.x >> 3;          // target within block
    const int s  = threadIdx.x & 7;           // sub-lane within target group
    const int tr = t0 + g;
    const float px = pos_skip[tr * 3 + 0], py = pos_skip[tr * 3 + 1], pz = pos_skip[tr * 3 + 2];
    const float pt2 = __fadd_rn(__fadd_rn(__fmul_rn(px, px), __fmul_rn(py, py)), __fmul_rn(pz, pz));
    float bd0 = 3e38f, bd1 = 3e38f, bd2 = 3e38f;
    int   bi0 = 0x7fffffff, bi1 = 0x7fffffff, bi2 = 0x7fffffff;
#pragma unroll 4
    for (int k = 0; k < NSRC / 8; ++k) {
        const int j = k * 8 + s;
        float4 sv = sp[j];
        // replicate reference's expanded formula ordering: (pt2 + ps2) - 2*dot
        float dot = __fadd_rn(__fadd_rn(__fmul_rn(px, sv.x), __fmul_rn(py, sv.y)), __fmul_rn(pz, sv.z));
        float d2  = __fsub_rn(__fadd_rn(pt2, sv.w), __fmul_rn(2.0f, dot));
        // branchless sorted-insert (strict <: earliest j wins ties within lane)
        bool c0 = d2 < bd0, c1 = d2 < bd1, c2 = d2 < bd2;
        bd2 = c1 ? bd1 : (c2 ? d2 : bd2);  bi2 = c1 ? bi1 : (c2 ? j : bi2);
        bd1 = c0 ? bd0 : (c1 ? d2 : bd1);  bi1 = c0 ? bi0 : (c1 ? j : bi1);
        bd0 = c0 ? d2  : bd0;              bi0 = c0 ? j  : bi0;
    }
    // butterfly merge across the 8 sub-lanes; lex (d, idx) preserves
    // the reference top_k smaller-index-first tie-break
#pragma unroll
    for (int m = 1; m <= 4; m <<= 1) {
        float od0 = __shfl_xor(bd0, m), od1 = __shfl_xor(bd1, m), od2 = __shfl_xor(bd2, m);
        int   oi0 = __shfl_xor(bi0, m), oi1 = __shfl_xor(bi1, m), oi2 = __shfl_xor(bi2, m);
#pragma unroll
        for (int e = 0; e < 3; ++e) {
            float d = e == 0 ? od0 : (e == 1 ? od1 : od2);
            int   i = e == 0 ? oi0 : (e == 1 ? oi1 : oi2);
            bool c0 = (d < bd0) || (d == bd0 && i < bi0);
            bool c1 = (d < bd1) || (d == bd1 && i < bi1);
            bool c2 = (d < bd2) || (d == bd2 && i < bi2);
            bd2 = c1 ? bd1 : (c2 ? d : bd2);  bi2 = c1 ? bi1 : (c2 ? i : bi2);
            bd1 = c0 ? bd0 : (c1 ? d : bd1);  bi1 = c0 ? bi0 : (c1 ? i : bi1);
            bd0 = c0 ? d   : bd0;             bi0 = c0 ? i  : bi0;
        }
    }
    if (s == 0) {
        idxo[tr * 3 + 0] = bi0; idxo[tr * 3 + 1] = bi1; idxo[tr * 3 + 2] = bi2;
        wo[tr * 3 + 0] = 1.0f / fmaxf(bd0, 1e-16f);
        wo[tr * 3 + 1] = 1.0f / fmaxf(bd1, 1e-16f);
        wo[tr * 3 + 2] = 1.0f / fmaxf(bd2, 1e-16f);
    }
}

// ---------------- interpolate + concat -> H0 (bf16, [MROWS][DIN]) ----------------
__global__ __launch_bounds__(256) void build_h_kernel(const float* __restrict__ x,
                                                      const float* __restrict__ xs,
                                                      const int* __restrict__ idxo,
                                                      const float* __restrict__ wo,
                                                      __hip_bfloat16* __restrict__ H0) {
    const int r    = blockIdx.x * 4 + (threadIdx.x >> 6);
    const int lane = threadIdx.x & 63;
    const int b    = r / NTGT;
    const float* xb = x + (size_t)b * NSRC * C_IN;
    const float w0 = wo[r * 3 + 0], w1 = wo[r * 3 + 1], w2 = wo[r * 3 + 2];
    const float inv = 1.0f / ((w0 + w1) + w2);
    const float* f0 = xb + (size_t)idxo[r * 3 + 0] * C_IN;
    const float* f1 = xb + (size_t)idxo[r * 3 + 1] * C_IN;
    const float* f2 = xb + (size_t)idxo[r * 3 + 2] * C_IN;
    __hip_bfloat16* o = H0 + (size_t)r * DIN;
#pragma unroll
    for (int k = 0; k < 4; ++k) {
        int c = lane + k * 64;
        float v = ((w0 * f0[c] + w1 * f1[c]) + w2 * f2[c]) * inv;
        o[c] = __float2bfloat16(v);
    }
    const float* srow = xs + (size_t)r * C_SKIP;
#pragma unroll
    for (int k = 0; k < 2; ++k) {
        int c = lane + k * 64;
        o[C_IN + c] = __float2bfloat16(srow[c]);
    }
}

// ---------------- W1 -> bf16 transposed [HID][DIN] ----------------
__global__ __launch_bounds__(256) void wconv1_kernel(const float* __restrict__ W1,
                                                     __hip_bfloat16* __restrict__ W1T) {
    int n = blockIdx.x;
    for (int k = threadIdx.x; k < DIN; k += 256)
        W1T[(size_t)n * DIN + k] = __float2bfloat16(W1[(size_t)k * HID + n]);
}

// ---------------- GEMM: out = relu(A @ W + bias), plus column sum/sumsq ----------------
// A: [MROWS][K] bf16 row-major; WT: [HID][K] bf16 (i.e. W transposed)
template <int K, bool OUT_BF16>
__global__ __launch_bounds__(256) void gemm_kernel(const __hip_bfloat16* __restrict__ A,
                                                   const __hip_bfloat16* __restrict__ WT,
                                                   const float* __restrict__ bias,
                                                   void* __restrict__ outp,
                                                   float* __restrict__ colsum,
                                                   float* __restrict__ colsq) {
    __shared__ short As[128 * 40];  // 128 rows x 32 cols, padded stride 40
    const int t = threadIdx.x;
    const int m0 = blockIdx.x * 128, n0 = blockIdx.y * 128;
    const int wid = t >> 6, lane = t & 63;
    const int wr = wid >> 1, wc = wid & 1;
    const int l15 = lane & 15, l4 = lane >> 4;
    f32x4 acc[4][4] = {};
    const short* Ash = (const short*)A;
    const short* Wsh = (const short*)WT;
    for (int kt = 0; kt < K / 32; ++kt) {
        __syncthreads();
#pragma unroll
        for (int c = t; c < 512; c += 256) {
            int row = c >> 2, col8 = (c & 3) * 8;
            short8 v = *(const short8*)(Ash + (size_t)(m0 + row) * K + kt * 32 + col8);
            *(short8*)(&As[row * 40 + col8]) = v;
        }
        __syncthreads();
        short8 af[4], bfr[4];
#pragma unroll
        for (int mi = 0; mi < 4; ++mi)
            af[mi] = *(const short8*)(&As[(wr * 64 + mi * 16 + l15) * 40 + l4 * 8]);
#pragma unroll
        for (int ni = 0; ni < 4; ++ni)
            bfr[ni] = *(const short8*)(Wsh + (size_t)(n0 + wc * 64 + ni * 16 + l15) * K + kt * 32 + l4 * 8);
#pragma unroll
        for (int mi = 0; mi < 4; ++mi)
#pragma unroll
            for (int ni = 0; ni < 4; ++ni)
                acc[mi][ni] = __builtin_amdgcn_mfma_f32_16x16x32_bf16(af[mi], bfr[ni], acc[mi][ni], 0, 0, 0);
    }
    // epilogue: bias + relu + store + column stats
    float bv[4];
    int col[4];
#pragma unroll
    for (int ni = 0; ni < 4; ++ni) {
        col[ni] = n0 + wc * 64 + ni * 16 + l15;
        bv[ni] = bias[col[ni]];
    }
    float csum[4] = {0, 0, 0, 0}, csq[4] = {0, 0, 0, 0};
    __hip_bfloat16* ob = (__hip_bfloat16*)outp;
    float* of = (float*)outp;
#pragma unroll
    for (int mi = 0; mi < 4; ++mi) {
#pragma unroll
        for (int r = 0; r < 4; ++r) {
            int rowg = m0 + wr * 64 + mi * 16 + l4 * 4 + r;  // D layout: row=(lane>>4)*4+reg
#pragma unroll
            for (int ni = 0; ni < 4; ++ni) {
                float v = fmaxf(acc[mi][ni][r] + bv[ni], 0.0f);
                if (OUT_BF16) ob[(size_t)rowg * HID + col[ni]] = __float2bfloat16(v);
                else          of[(size_t)rowg * HID + col[ni]] = v;
                csum[ni] += v;
                csq[ni] += v * v;
            }
        }
    }
#pragma unroll
    for (int ni = 0; ni < 4; ++ni) {
        float s = csum[ni], q = csq[ni];
        s += __shfl_xor(s, 16); s += __shfl_xor(s, 32);
        q += __shfl_xor(q, 16); q += __shfl_xor(q, 32);
        if (l4 == 0) {
            atomicAdd(&colsum[col[ni]], s);
            atomicAdd(&colsq[col[ni]], q);
        }
    }
}

// ---------------- BN stats -> scale/shift ----------------
__global__ void finalize_kernel(const float* __restrict__ sum, const float* __restrict__ sq,
                                const float* __restrict__ g, const float* __restrict__ be,
                                float* __restrict__ scale, float* __restrict__ shift) {
    int c = threadIdx.x;
    float mu  = sum[c] * (1.0f / MROWS);
    float var = sq[c] * (1.0f / MROWS) - mu * mu;
    float inv = 1.0f / sqrtf(var + 1e-5f);
    float sc = g[c] * inv;
    scale[c] = sc;
    shift[c] = be[c] - mu * sc;
}

// ---------------- fold BN1 into W2: W2T'[n][k] = scale1[k]*W2[k][n]; bias2' = b2 + shift1@W2 ----------------
__global__ __launch_bounds__(256) void foldw2_kernel(const float* __restrict__ W2,
                                                     const float* __restrict__ b2,
                                                     const float* __restrict__ scale1,
                                                     const float* __restrict__ shift1,
                                                     __hip_bfloat16* __restrict__ W2T,
                                                     float* __restrict__ bias2f) {
    __shared__ float red[256];
    int n = blockIdx.x, k = threadIdx.x;
    float v = W2[(size_t)k * HID + n];
    W2T[(size_t)n * HID + k] = __float2bfloat16(scale1[k] * v);
    red[k] = shift1[k] * v;
    __syncthreads();
    for (int s = 128; s > 0; s >>= 1) {
        if (k < s) red[k] += red[k + s];
        __syncthreads();
    }
    if (k == 0) bias2f[n] = b2[n] + red[0];
}

// ---------------- final BN2 applied in place on d_out (fp32) ----------------
__global__ __launch_bounds__(256) void bn2_kernel(float* __restrict__ out,
                                                  const float* __restrict__ scale2,
                                                  const float* __restrict__ shift2) {
    int idx = blockIdx.x * blockDim.x + threadIdx.x;  // float4 index
    const int total = MROWS * HID / 4;
    for (; idx < total; idx += gridDim.x * blockDim.x) {
        float4 v = ((float4*)out)[idx];
        int c = (idx * 4) & (HID - 1);
        float4 sc = *(const float4*)(scale2 + c);
        float4 sh = *(const float4*)(shift2 + c);
        v.x = sc.x * v.x + sh.x;
        v.y = sc.y * v.y + sh.y;
        v.z = sc.z * v.z + sh.z;
        v.w = sc.w * v.w + sh.w;
        ((float4*)out)[idx] = v;
    }
}

extern "C" void kernel_launch(void* const* d_in, const int* in_sizes, int n_in,
                              void* d_out, int out_size, void* d_ws, size_t ws_size,
                              hipStream_t stream) {
    const float* x    = (const float*)d_in[0];
    const float* pos  = (const float*)d_in[1];
    const float* xs   = (const float*)d_in[3];
    const float* poss = (const float*)d_in[4];
    const float* W1   = (const float*)d_in[6];
    const float* b1   = (const float*)d_in[7];
    const float* g1   = (const float*)d_in[8];
    const float* be1  = (const float*)d_in[9];
    const float* W2   = (const float*)d_in[10];
    const float* b2   = (const float*)d_in[11];
    const float* g2   = (const float*)d_in[12];
    const float* be2  = (const float*)d_in[13];

    char* ws = (char*)d_ws;
    size_t off = 0;
    auto alloc = [&](size_t bytes) -> void* {
        void* p = ws + off;
        off += (bytes + 255) & ~(size_t)255;
        return p;
    };
    int*            idxo  = (int*)alloc((size_t)MROWS * 3 * sizeof(int));
    float*          wo    = (float*)alloc((size_t)MROWS * 3 * sizeof(float));
    __hip_bfloat16* W1T   = (__hip_bfloat16*)alloc((size_t)HID * DIN * 2);
    __hip_bfloat16* W2T   = (__hip_bfloat16*)alloc((size_t)HID * HID * 2);
    float*          stats = (float*)alloc(4 * HID * sizeof(float));
    float *sum1 = stats, *sq1 = stats + HID, *sum2 = stats + 2 * HID, *sq2 = stats + 3 * HID;
    float* sc = (float*)alloc(5 * HID * sizeof(float));
    float *scale1 = sc, *shift1 = sc + HID, *scale2 = sc + 2 * HID, *shift2 = sc + 3 * HID,
          *bias2f = sc + 4 * HID;
    __hip_bfloat16* H0 = (__hip_bfloat16*)alloc((size_t)MROWS * DIN * 2);
    __hip_bfloat16* H1 = (__hip_bfloat16*)alloc((size_t)MROWS * HID * 2);

    hipMemsetAsync(stats, 0, 4 * HID * sizeof(float), stream);

    knn_kernel<<<MROWS / 32, 256, 0, stream>>>(pos, poss, idxo, wo);
    build_h_kernel<<<MROWS / 4, 256, 0, stream>>>(x, xs, idxo, wo, H0);
    wconv1_kernel<<<HID, 256, 0, stream>>>(W1, W1T);
    gemm_kernel<DIN, true><<<dim3(MROWS / 128, 2), 256, 0, stream>>>(H0, W1T, b1, H1, sum1, sq1);
    finalize_kernel<<<1, 256, 0, stream>>>(sum1, sq1, g1, be1, scale1, shift1);
    foldw2_kernel<<<HID, 256, 0, stream>>>(W2, b2, scale1, shift1, W2T, bias2f);
    gemm_kernel<HID, false><<<dim3(MROWS / 128, 2), 256, 0, stream>>>(H1, W2T, bias2f, d_out, sum2, sq2);
    finalize_kernel<<<1, 256, 0, stream>>>(sum2, sq2, g2, be2, scale2, shift2);
    bn2_kernel<<<2048, 256, 0, stream>>>((float*)d_out, scale2, shift2);
}